// Round 4
// baseline (295.367 us; speedup 1.0000x reference)
//
#include <hip/hip_runtime.h>
#include <hip/hip_bf16.h>

typedef __attribute__((ext_vector_type(8))) short short8;
typedef __attribute__((ext_vector_type(4))) float f32x4;

__device__ __forceinline__ ushort f2bf(float f) {
    union { float f; uint u; } v; v.f = f;
    uint u = v.u;
    return (ushort)((u + 0x7fffu + ((u >> 16) & 1u)) >> 16);  // RNE
}
__device__ __forceinline__ float bf_lo(uint u) { return __uint_as_float(u << 16); }
__device__ __forceinline__ float bf_hi(uint u) { return __uint_as_float(u & 0xffff0000u); }

// ---------------------------------------------------------------------------
// bf16 MFMA GEMM body (gemm1 only): Y[n,COLS](bf16) = X[n,128] @ Wt[COLS][128]
// Epilogue pre-scales each output row r by rsqrt(deg[r]+1) so the following
// aggregation is weight-free. smem >= (64+COLS)*136*2 B. 256-thread blocks.
// ---------------------------------------------------------------------------
template <int COLS, bool F32IN>
__device__ __forceinline__ void gemm_body(const void* __restrict__ Xin,
                                          const ushort* __restrict__ Wt,
                                          ushort* __restrict__ Y, int n,
                                          int bid, char* smem,
                                          const int* __restrict__ deg) {
    constexpr int LDW = 136;  // +8 pad
    ushort* sX = (ushort*)smem;
    ushort* sW = sX + 64 * LDW;
    const int tid = threadIdx.x;
    const int row0 = bid * 64;

    if (F32IN) {
        const float* Xf = (const float*)Xin;
#pragma unroll
        for (int i = 0; i < 8; ++i) {
            int idx = i * 256 + tid;
            int r = idx >> 5, kc = idx & 31;
            int gr = min(row0 + r, n - 1);
            float4 v = *(const float4*)&Xf[(size_t)gr * 128 + kc * 4];
            ushort4 o;
            o.x = f2bf(v.x); o.y = f2bf(v.y); o.z = f2bf(v.z); o.w = f2bf(v.w);
            *(ushort4*)&sX[r * LDW + kc * 4] = o;
        }
    } else {
        const ushort* Xb = (const ushort*)Xin;
#pragma unroll
        for (int i = 0; i < 4; ++i) {
            int idx = i * 256 + tid;
            int r = idx >> 4, kc = idx & 15;
            int gr = min(row0 + r, n - 1);
            uint4 v = *(const uint4*)&Xb[(size_t)gr * 128 + kc * 8];
            *(uint4*)&sX[r * LDW + kc * 8] = v;
        }
    }
#pragma unroll
    for (int c = tid; c < COLS * 16; c += 256) {
        int r = c >> 4, kc = c & 15;
        uint4 v = *(const uint4*)&Wt[(size_t)r * 128 + kc * 8];
        *(uint4*)&sW[r * LDW + kc * 8] = v;
    }
    __syncthreads();

    constexpr int NT = (COLS == 128) ? 2 : 1;
    constexpr int WN = COLS / 4;
    const int w = tid >> 6;
    const int lane = tid & 63;
    const int lm = lane & 15;
    const int kq = lane >> 4;

    f32x4 acc[4][NT];
#pragma unroll
    for (int mt = 0; mt < 4; ++mt)
#pragma unroll
        for (int ntn = 0; ntn < NT; ++ntn) acc[mt][ntn] = (f32x4){0.f, 0.f, 0.f, 0.f};

#pragma unroll
    for (int ks = 0; ks < 4; ++ks) {
        const int k0 = ks * 32 + kq * 8;
        short8 bfr[NT];
#pragma unroll
        for (int ntn = 0; ntn < NT; ++ntn)
            bfr[ntn] = *(const short8*)&sW[(w * WN + ntn * 16 + lm) * LDW + k0];
#pragma unroll
        for (int mt = 0; mt < 4; ++mt) {
            short8 afr = *(const short8*)&sX[(mt * 16 + lm) * LDW + k0];
#pragma unroll
            for (int ntn = 0; ntn < NT; ++ntn)
                acc[mt][ntn] = __builtin_amdgcn_mfma_f32_16x16x32_bf16(afr, bfr[ntn], acc[mt][ntn], 0, 0, 0);
        }
    }

#pragma unroll
    for (int mt = 0; mt < 4; ++mt) {
        int r_base = row0 + mt * 16 + kq * 4;
#pragma unroll
        for (int rr = 0; rr < 4; ++rr) {
            int r = r_base + rr;
            if (r < n) {
                float dr = rsqrtf((float)(deg[r] + 1));
#pragma unroll
                for (int ntn = 0; ntn < NT; ++ntn) {
                    int col = w * WN + ntn * 16 + lm;
                    Y[(size_t)r * COLS + col] = f2bf(acc[mt][ntn][rr] * dr);
                }
            }
        }
    }
}

// ---------------------------------------------------------------------------
// CSR build phase 1: coarse partition by dst>>8 (+fused weight cast tail)
// + global per-node degree count (deg), so gemm1 can pre-scale its output.
// Edges packed (dst<<16)|src. PCHUNK=1024 -> 782 blocks.
// ---------------------------------------------------------------------------
#define PCHUNK 1024

__global__ __launch_bounds__(256) void k_partition(const int* __restrict__ src,
                                                   const int* __restrict__ dst, int E,
                                                   int nbuck, int cap, int pblocks,
                                                   int* __restrict__ gcur,
                                                   uint* __restrict__ part,
                                                   int* __restrict__ deg,
                                                   const float* __restrict__ W1,
                                                   const float* __restrict__ W2,
                                                   const float* __restrict__ W3,
                                                   ushort* __restrict__ wt1,
                                                   ushort* __restrict__ wt2,
                                                   ushort* __restrict__ wt3) {
    __shared__ int hist[256];
    __shared__ int base[256];
    __shared__ int cnt2[256];
    const int tid = threadIdx.x;

    if ((int)blockIdx.x >= pblocks) {
        int i = (blockIdx.x - pblocks) * 256 + tid;
        if (i < 16384) {
            int k = i >> 7, nn = i & 127;
            wt1[nn * 128 + k] = f2bf(W1[i]);
        } else if (i < 32768) {
            int j = i - 16384;
            int k = j >> 7, nn = j & 127;
            wt2[nn * 128 + k] = f2bf(W2[j]);
        } else if (i < 40960) {
            int j = i - 32768;
            int k = j >> 6, nn = j & 63;
            wt3[nn * 128 + k] = f2bf(W3[j]);
        }
        return;
    }

    const int s0 = blockIdx.x * PCHUNK;
    const int send = min(s0 + PCHUNK, E);
    hist[tid] = 0;
    cnt2[tid] = 0;
    __syncthreads();
    for (int i = s0 + tid; i < send; i += 256) {
        int d = dst[i];
        atomicAdd(&hist[d >> 8], 1);
        atomicAdd(&deg[d], 1);  // fire-and-forget global atomic
    }
    __syncthreads();
    if (tid < nbuck && hist[tid] > 0) base[tid] = atomicAdd(&gcur[tid], hist[tid]);
    __syncthreads();
    for (int i = s0 + tid; i < send; i += 256) {
        int d = dst[i];
        int s = src[i];
        int k = d >> 8;
        int r = base[k] + atomicAdd(&cnt2[k], 1);
        if (r < cap) part[(size_t)k * cap + r] = ((uint)d << 16) | (uint)s;
    }
}

// ---------------------------------------------------------------------------
// CSR build phase 2 (+fused GEMM1 tail blocks).
// ---------------------------------------------------------------------------
__global__ __launch_bounds__(256) void k_sort_gemm1(const uint* __restrict__ part,
                                                    const int* __restrict__ gcur,
                                                    int nbuck, int cap, int n,
                                                    int* __restrict__ rowptr,
                                                    int* __restrict__ csr,
                                                    const float* __restrict__ x,
                                                    const ushort* __restrict__ wt1,
                                                    ushort* __restrict__ bufA,
                                                    const int* __restrict__ deg) {
    __shared__ char smem[(64 + 128) * 136 * 2];  // 52.2 KB union
    const int tid = threadIdx.x;

    if ((int)blockIdx.x >= nbuck) {
        gemm_body<128, true>(x, wt1, bufA, n, blockIdx.x - nbuck, smem, deg);
        return;
    }

    int* hist  = (int*)smem;          // 256 ints
    int* pfx   = hist + 256;
    int* sscan = pfx + 256;
    const int b = blockIdx.x;

    int gv = (tid < nbuck) ? min(gcur[tid], cap) : 0;
    sscan[tid] = gv;
    __syncthreads();
    for (int off = 1; off < 256; off <<= 1) {
        int t = (tid >= off) ? sscan[tid - off] : 0;
        __syncthreads();
        sscan[tid] += t;
        __syncthreads();
    }
    const int outbase = (b == 0) ? 0 : sscan[b - 1];
    const int sz = min(gcur[b], cap);
    const uint* seg = part + (size_t)b * cap;

    hist[tid] = 0;
    __syncthreads();
    for (int i = tid; i < sz; i += 256) atomicAdd(&hist[(seg[i] >> 16) & 255], 1);
    __syncthreads();

    int cnt_t = hist[tid];
    pfx[tid] = cnt_t;
    __syncthreads();
    for (int off = 1; off < 256; off <<= 1) {
        int t = (tid >= off) ? pfx[tid - off] : 0;
        __syncthreads();
        pfx[tid] += t;
        __syncthreads();
    }
    int excl = pfx[tid] - cnt_t;

    int node = b * 256 + tid;
    if (node < n) {
        rowptr[node] = outbase + excl;
        if (node == n - 1) rowptr[n] = outbase + excl + cnt_t;
    }
    __syncthreads();
    pfx[tid] = excl;
    hist[tid] = 0;
    __syncthreads();
    for (int i = tid; i < sz; i += 256) {
        uint p = seg[i];
        int j = (p >> 16) & 255;
        int r = atomicAdd(&hist[j], 1);
        csr[outbase + pfx[j] + r] = (int)(p & 0xffffu);
    }
}

// ---------------------------------------------------------------------------
// Fused agg + GEMM: one block = 64 nodes, 512 threads = 8 waves.
// Stage A: weight-free gather (input rows pre-scaled by their own rsqrt(deg+1));
//   every edge tile handled by full 16-batches + ONE predicated 16-batch
//   (padding lanes gather row 0 -> L1-hot -> free; masked by cndmask).
// Stage B: MFMA 64x[COLS], B-frags from global Wt; epilogue writes
//   Y[r] = rsqrt(deg[r]+1) * acc  (pre-scaled for the NEXT aggregation).
// ---------------------------------------------------------------------------
template <int COLS>
__global__ __launch_bounds__(512) void agg_gemm(const ushort* __restrict__ H,
                                                const int* __restrict__ deg,
                                                const int* __restrict__ rowptr,
                                                const int* __restrict__ csr,
                                                const float* __restrict__ bias,
                                                const ushort* __restrict__ Wt,
                                                ushort* __restrict__ Y, int n) {
    __shared__ ushort sX[64 * 136];  // 17408 B
    const int tid = threadIdx.x;
    const int wv = tid >> 6;    // 0..7
    const int lane = tid & 63;
    const int row0 = blockIdx.x * 64;
    const uint* Hu = (const uint*)H;  // row = 64 uints (128 bf16)
    const float2 bv = ((const float2*)bias)[lane];
    const int vb = row0 + wv * 8;

#pragma unroll 1
    for (int i = 0; i < 8; ++i) {
        const int v = min(vb + i, n - 1);  // clamp: dup rows discarded at write
        // independent loads issue first; consumed at end
        uint h0 = Hu[(size_t)v * 64 + lane];
        const int dgv = deg[v];
        const int e0 = rowptr[v];
        const int e1 = rowptr[v + 1];

        float ax = 0.f, ay = 0.f;
        int e = e0;
        while (e < e1) {
            const int c = min(e1 - e, 64);
            int sidx = 0;
            if (lane < c) sidx = csr[e + lane];
            int j = 0;
            for (; j + 16 <= c; j += 16) {
                uint hv[16];
#pragma unroll
                for (int u = 0; u < 16; ++u) {
                    int s = __builtin_amdgcn_readlane(sidx, j + u);
                    hv[u] = Hu[(size_t)s * 64 + lane];
                }
#pragma unroll
                for (int u = 0; u < 16; ++u) { ax += bf_lo(hv[u]); ay += bf_hi(hv[u]); }
            }
            if (j < c) {  // one predicated 16-batch covers remainder 1..15
                uint hv[16];
#pragma unroll
                for (int u = 0; u < 16; ++u) {
                    int s = __builtin_amdgcn_readlane(sidx, j + u);  // pad lanes: s=0 (L1-hot row)
                    hv[u] = Hu[(size_t)s * 64 + lane];
                }
#pragma unroll
                for (int u = 0; u < 16; ++u) {
                    uint hm = (j + u < c) ? hv[u] : 0u;
                    ax += bf_lo(hm); ay += bf_hi(hm);
                }
            }
            e += c;
        }

        // self term (pre-scaled row v) + final dv scale + bias + relu
        ax += bf_lo(h0); ay += bf_hi(h0);
        const float dv = rsqrtf((float)(dgv + 1));
        float rx = fmaxf(dv * ax + bv.x, 0.f);
        float ry = fmaxf(dv * ay + bv.y, 0.f);
        ((uint*)sX)[(wv * 8 + i) * 68 + lane] = (uint)f2bf(rx) | ((uint)f2bf(ry) << 16);
    }
    __syncthreads();

    // ---- stage B ----
    constexpr int NT = COLS / 64;      // 2 (COLS=128) or 1 (COLS=64)
    constexpr int WN = COLS / 4;       // cols per wave
    const int wr = wv >> 2;            // 0..1
    const int wc = wv & 3;             // 0..3
    const int lm = lane & 15;
    const int kq = lane >> 4;

    f32x4 acc[2][NT];
#pragma unroll
    for (int mt = 0; mt < 2; ++mt)
#pragma unroll
        for (int ntn = 0; ntn < NT; ++ntn) acc[mt][ntn] = (f32x4){0.f, 0.f, 0.f, 0.f};

#pragma unroll
    for (int ks = 0; ks < 4; ++ks) {
        const int k0 = ks * 32 + kq * 8;
        short8 bfr[NT];
#pragma unroll
        for (int ntn = 0; ntn < NT; ++ntn)
            bfr[ntn] = *(const short8*)&Wt[(size_t)(wc * WN + ntn * 16 + lm) * 128 + k0];
#pragma unroll
        for (int mt = 0; mt < 2; ++mt) {
            short8 afr = *(const short8*)&sX[((wr * 2 + mt) * 16 + lm) * 136 + k0];
#pragma unroll
            for (int ntn = 0; ntn < NT; ++ntn)
                acc[mt][ntn] = __builtin_amdgcn_mfma_f32_16x16x32_bf16(afr, bfr[ntn], acc[mt][ntn], 0, 0, 0);
        }
    }

    // epilogue: pre-scale each output row by rsqrt(deg+1) -> next agg weight-free
#pragma unroll
    for (int mt = 0; mt < 2; ++mt) {
        int r_base = row0 + (wr * 2 + mt) * 16 + kq * 4;
#pragma unroll
        for (int rr = 0; rr < 4; ++rr) {
            int r = r_base + rr;
            if (r < n) {
                float dr = rsqrtf((float)(deg[r] + 1));
#pragma unroll
                for (int ntn = 0; ntn < NT; ++ntn) {
                    int col = wc * WN + ntn * 16 + lm;
                    Y[(size_t)r * COLS + col] = f2bf(acc[mt][ntn][rr] * dr);
                }
            }
        }
    }
}

// ---------------------------------------------------------------------------
// agg64 + row-normalize (final GCN layer), target_mlp fused as tail blocks.
// Input bufC pre-scaled -> weight-free gather with predicated 16-batches.
// ---------------------------------------------------------------------------
__global__ __launch_bounds__(256) void agg64_final(const ushort* __restrict__ H,
                                                   const int* __restrict__ deg,
                                                   const int* __restrict__ rowptr,
                                                   const int* __restrict__ csr,
                                                   const float* __restrict__ bias,
                                                   float* __restrict__ out, int n, int agrid,
                                                   const float* __restrict__ y,
                                                   const float* __restrict__ gamma,
                                                   const float* __restrict__ beta,
                                                   const float* __restrict__ Wm1,
                                                   const float* __restrict__ bm1,
                                                   const float* __restrict__ Wm2,
                                                   const float* __restrict__ bm2,
                                                   float* __restrict__ out_y) {
    __shared__ float red[256];
    __shared__ float t1[128];
    __shared__ float s_mu, s_var;
    const int tid = threadIdx.x;

    if ((int)blockIdx.x >= agrid) {
        float yv = y[tid];
        red[tid] = yv;
        __syncthreads();
        for (int s = 128; s > 0; s >>= 1) {
            if (tid < s) red[tid] += red[tid + s];
            __syncthreads();
        }
        if (tid == 0) s_mu = red[0] * (1.0f / 256.0f);
        __syncthreads();
        float mu = s_mu;
        float d = yv - mu;
        red[tid] = d * d;
        __syncthreads();
        for (int s = 128; s > 0; s >>= 1) {
            if (tid < s) red[tid] += red[tid + s];
            __syncthreads();
        }
        if (tid == 0) s_var = red[0] * (1.0f / 256.0f);
        __syncthreads();

        const int row = blockIdx.x - agrid;
        float yb = (y[row] - mu) * rsqrtf(s_var + 1e-5f) * gamma[0] + beta[0];
        if (tid < 128) t1[tid] = fmaxf(yb * Wm1[tid] + bm1[tid], 0.0f);
        __syncthreads();
        if (tid < 64) {
            float acc = bm2[tid];
#pragma unroll 8
            for (int c = 0; c < 128; ++c) acc += t1[c] * Wm2[c * 64 + tid];
            float ss = acc * acc;
#pragma unroll
            for (int m = 1; m < 64; m <<= 1) ss += __shfl_xor(ss, m, 64);
            out_y[row * 64 + tid] = acc / fmaxf(sqrtf(ss), 1e-12f);
        }
        return;
    }

    const int wid = blockIdx.x * 4 + (tid >> 6);
    const int lane = tid & 63;
    if (wid >= n) return;
    const int v = wid;
    // independent loads issue together; self term consumed at end
    ushort h0 = H[(size_t)v * 64 + lane];
    const int dgv = deg[v];
    const int e0 = rowptr[v];
    const int e1 = rowptr[v + 1];

    float acc = 0.0f;
    int e = e0;
    while (e < e1) {
        const int c = min(e1 - e, 64);
        int sidx = 0;
        if (lane < c) sidx = csr[e + lane];
        int j = 0;
        for (; j + 16 <= c; j += 16) {
            ushort hv[16];
#pragma unroll
            for (int u = 0; u < 16; ++u) {
                int s = __builtin_amdgcn_readlane(sidx, j + u);
                hv[u] = H[(size_t)s * 64 + lane];
            }
#pragma unroll
            for (int u = 0; u < 16; ++u) acc += bf_lo((uint)hv[u]);
        }
        if (j < c) {
            ushort hv[16];
#pragma unroll
            for (int u = 0; u < 16; ++u) {
                int s = __builtin_amdgcn_readlane(sidx, j + u);
                hv[u] = H[(size_t)s * 64 + lane];
            }
#pragma unroll
            for (int u = 0; u < 16; ++u) {
                uint hm = (j + u < c) ? (uint)hv[u] : 0u;
                acc += bf_lo(hm);
            }
        }
        e += c;
    }

    acc += bf_lo((uint)h0);  // pre-scaled self term
    const float dv = rsqrtf((float)(dgv + 1));
    float r = dv * acc + bias[lane];
    float ss = r * r;
#pragma unroll
    for (int m = 1; m < 64; m <<= 1) ss += __shfl_xor(ss, m, 64);
    r = r / fmaxf(sqrtf(ss), 1e-12f);
    out[(size_t)v * 64 + lane] = r;
}

// ---------------------------------------------------------------------------
extern "C" void kernel_launch(void* const* d_in, const int* in_sizes, int n_in,
                              void* d_out, int out_size, void* d_ws, size_t ws_size,
                              hipStream_t stream) {
    const float* x     = (const float*)d_in[0];
    const float* y     = (const float*)d_in[1];
    const int*   edge  = (const int*)d_in[2];
    const float* W1    = (const float*)d_in[3];
    const float* b1    = (const float*)d_in[4];
    const float* W2    = (const float*)d_in[5];
    const float* b2    = (const float*)d_in[6];
    const float* W3    = (const float*)d_in[7];
    const float* b3    = (const float*)d_in[8];
    const float* bng   = (const float*)d_in[9];
    const float* bnb   = (const float*)d_in[10];
    const float* Wm1   = (const float*)d_in[11];
    const float* bm1   = (const float*)d_in[12];
    const float* Wm2   = (const float*)d_in[13];
    const float* bm2   = (const float*)d_in[14];

    const int n = in_sizes[0] / 128;  // 50000
    const int E = in_sizes[2] / 2;    // 800000
    const int* src = edge;
    const int* dst = edge + E;

    const int nbuck = (n + 255) / 256;                 // 196
    const int cap = E / nbuck + E / nbuck / 4 + 1024;  // mean + 25% + slack

    size_t off = 0;
    auto carve = [&](size_t bytes) {
        size_t p = off;
        off = (off + bytes + 255) & ~(size_t)255;
        return p;
    };
    char* ws = (char*)d_ws;
    int*    gcur    = (int*)(ws + carve(256 * 4));
    int*    deg     = (int*)(ws + carve((size_t)n * 4));  // contiguous after gcur
    uint*   part    = (uint*)(ws + carve((size_t)nbuck * cap * 4));
    int*    rowptr  = (int*)(ws + carve((size_t)(n + 1) * 4));
    int*    csr     = (int*)(ws + carve((size_t)E * 4));
    ushort* wt1     = (ushort*)(ws + carve(128 * 128 * 2));
    ushort* wt2     = (ushort*)(ws + carve(128 * 128 * 2));
    ushort* wt3     = (ushort*)(ws + carve(64 * 128 * 2));
    ushort* bufA    = (ushort*)(ws + carve((size_t)n * 128 * 2));
    ushort* bufB    = (ushort*)(ws + carve((size_t)n * 128 * 2));
    ushort* bufC    = (ushort*)(ws + carve((size_t)n * 64 * 2));
    (void)ws_size; (void)n_in; (void)out_size;

    float* x_emb = (float*)d_out;
    float* y_emb = (float*)d_out + (size_t)n * 64;

    const int pblocks = (E + PCHUNK - 1) / PCHUNK;  // 782
    const int ggrid = (n + 63) / 64;                // 782
    const int agrid = (n + 3) / 4;                  // 12500

    // zero gcur + deg in one shot (contiguous carve)
    hipMemsetAsync(gcur, 0, 1024 + (size_t)n * 4, stream);
    k_partition<<<pblocks + 160, 256, 0, stream>>>(src, dst, E, nbuck, cap, pblocks,
                                                   gcur, part, deg, W1, W2, W3, wt1, wt2, wt3);
    // bucket sort (196 blocks) + gemm1 (782 blocks, pre-scaled epilogue) concurrently
    k_sort_gemm1<<<nbuck + ggrid, 256, 0, stream>>>(part, gcur, nbuck, cap, n,
                                                    rowptr, csr, x, wt1, bufA, deg);

    // fused: agg(layer1, weight-free) -> GEMM W2, write bufB pre-scaled
    agg_gemm<128><<<ggrid, 512, 0, stream>>>(bufA, deg, rowptr, csr, b1, wt2, bufB, n);
    // fused: agg(layer2, weight-free) -> GEMM W3, write bufC pre-scaled
    agg_gemm<64><<<ggrid, 512, 0, stream>>>(bufB, deg, rowptr, csr, b2, wt3, bufC, n);
    // final agg (weight-free) + normalize (+ target MLP tail blocks)
    agg64_final<<<agrid + 256, 256, 0, stream>>>(bufC, deg, rowptr, csr, b3, x_emb, n, agrid,
                                                 y, bng, bnb, Wm1, bm1, Wm2, bm2, y_emb);
}

// Round 5
// 253.048 us; speedup vs baseline: 1.1672x; 1.1672x over previous
//
#include <hip/hip_runtime.h>
#include <hip/hip_bf16.h>

typedef __attribute__((ext_vector_type(8))) short short8;
typedef __attribute__((ext_vector_type(4))) float f32x4;

__device__ __forceinline__ ushort f2bf(float f) {
    union { float f; uint u; } v; v.f = f;
    uint u = v.u;
    return (ushort)((u + 0x7fffu + ((u >> 16) & 1u)) >> 16);  // RNE
}
__device__ __forceinline__ float bf_lo(uint u) { return __uint_as_float(u << 16); }
__device__ __forceinline__ float bf_hi(uint u) { return __uint_as_float(u & 0xffff0000u); }
__device__ __forceinline__ float lane_bcast_f(float v, int j) {
    return __uint_as_float(__builtin_amdgcn_readlane(__float_as_uint(v), j));
}

// ---------------------------------------------------------------------------
// bf16 MFMA GEMM body (gemm1 only): Y[n,COLS](bf16) = X[n,128] @ Wt[COLS][128]
// Unscaled output. smem >= (64+COLS)*136*2 B. 256-thread blocks.
// ---------------------------------------------------------------------------
template <int COLS, bool F32IN>
__device__ __forceinline__ void gemm_body(const void* __restrict__ Xin,
                                          const ushort* __restrict__ Wt,
                                          ushort* __restrict__ Y, int n,
                                          int bid, char* smem) {
    constexpr int LDW = 136;  // +8 pad
    ushort* sX = (ushort*)smem;
    ushort* sW = sX + 64 * LDW;
    const int tid = threadIdx.x;
    const int row0 = bid * 64;

    if (F32IN) {
        const float* Xf = (const float*)Xin;
#pragma unroll
        for (int i = 0; i < 8; ++i) {
            int idx = i * 256 + tid;
            int r = idx >> 5, kc = idx & 31;
            int gr = min(row0 + r, n - 1);
            float4 v = *(const float4*)&Xf[(size_t)gr * 128 + kc * 4];
            ushort4 o;
            o.x = f2bf(v.x); o.y = f2bf(v.y); o.z = f2bf(v.z); o.w = f2bf(v.w);
            *(ushort4*)&sX[r * LDW + kc * 4] = o;
        }
    } else {
        const ushort* Xb = (const ushort*)Xin;
#pragma unroll
        for (int i = 0; i < 4; ++i) {
            int idx = i * 256 + tid;
            int r = idx >> 4, kc = idx & 15;
            int gr = min(row0 + r, n - 1);
            uint4 v = *(const uint4*)&Xb[(size_t)gr * 128 + kc * 8];
            *(uint4*)&sX[r * LDW + kc * 8] = v;
        }
    }
#pragma unroll
    for (int c = tid; c < COLS * 16; c += 256) {
        int r = c >> 4, kc = c & 15;
        uint4 v = *(const uint4*)&Wt[(size_t)r * 128 + kc * 8];
        *(uint4*)&sW[r * LDW + kc * 8] = v;
    }
    __syncthreads();

    constexpr int NT = (COLS == 128) ? 2 : 1;
    constexpr int WN = COLS / 4;
    const int w = tid >> 6;
    const int lane = tid & 63;
    const int lm = lane & 15;
    const int kq = lane >> 4;

    f32x4 acc[4][NT];
#pragma unroll
    for (int mt = 0; mt < 4; ++mt)
#pragma unroll
        for (int ntn = 0; ntn < NT; ++ntn) acc[mt][ntn] = (f32x4){0.f, 0.f, 0.f, 0.f};

#pragma unroll
    for (int ks = 0; ks < 4; ++ks) {
        const int k0 = ks * 32 + kq * 8;
        short8 bfr[NT];
#pragma unroll
        for (int ntn = 0; ntn < NT; ++ntn)
            bfr[ntn] = *(const short8*)&sW[(w * WN + ntn * 16 + lm) * LDW + k0];
#pragma unroll
        for (int mt = 0; mt < 4; ++mt) {
            short8 afr = *(const short8*)&sX[(mt * 16 + lm) * LDW + k0];
#pragma unroll
            for (int ntn = 0; ntn < NT; ++ntn)
                acc[mt][ntn] = __builtin_amdgcn_mfma_f32_16x16x32_bf16(afr, bfr[ntn], acc[mt][ntn], 0, 0, 0);
        }
    }

#pragma unroll
    for (int mt = 0; mt < 4; ++mt) {
        int r_base = row0 + mt * 16 + kq * 4;
#pragma unroll
        for (int ntn = 0; ntn < NT; ++ntn) {
            int col = w * WN + ntn * 16 + lm;
#pragma unroll
            for (int rr = 0; rr < 4; ++rr) {
                int r = r_base + rr;
                if (r < n) Y[(size_t)r * COLS + col] = f2bf(acc[mt][ntn][rr]);
            }
        }
    }
}

// ---------------------------------------------------------------------------
// CSR build phase 1: coarse partition by dst>>8 (+fused weight cast tail).
// Edges packed (dst<<16)|src. No global atomics. PCHUNK=1024 -> 782 blocks.
// ---------------------------------------------------------------------------
#define PCHUNK 1024

__global__ __launch_bounds__(256) void k_partition(const int* __restrict__ src,
                                                   const int* __restrict__ dst, int E,
                                                   int nbuck, int cap, int pblocks,
                                                   int* __restrict__ gcur,
                                                   uint* __restrict__ part,
                                                   const float* __restrict__ W1,
                                                   const float* __restrict__ W2,
                                                   const float* __restrict__ W3,
                                                   ushort* __restrict__ wt1,
                                                   ushort* __restrict__ wt2,
                                                   ushort* __restrict__ wt3) {
    __shared__ int hist[256];
    __shared__ int base[256];
    __shared__ int cnt2[256];
    const int tid = threadIdx.x;

    if ((int)blockIdx.x >= pblocks) {
        int i = (blockIdx.x - pblocks) * 256 + tid;
        if (i < 16384) {
            int k = i >> 7, nn = i & 127;
            wt1[nn * 128 + k] = f2bf(W1[i]);
        } else if (i < 32768) {
            int j = i - 16384;
            int k = j >> 7, nn = j & 127;
            wt2[nn * 128 + k] = f2bf(W2[j]);
        } else if (i < 40960) {
            int j = i - 32768;
            int k = j >> 6, nn = j & 63;
            wt3[nn * 128 + k] = f2bf(W3[j]);
        }
        return;
    }

    const int s0 = blockIdx.x * PCHUNK;
    const int send = min(s0 + PCHUNK, E);
    hist[tid] = 0;
    cnt2[tid] = 0;
    __syncthreads();
    for (int i = s0 + tid; i < send; i += 256) {
        int d = dst[i];
        atomicAdd(&hist[d >> 8], 1);
    }
    __syncthreads();
    if (tid < nbuck && hist[tid] > 0) base[tid] = atomicAdd(&gcur[tid], hist[tid]);
    __syncthreads();
    for (int i = s0 + tid; i < send; i += 256) {
        int d = dst[i];
        int s = src[i];
        int k = d >> 8;
        int r = base[k] + atomicAdd(&cnt2[k], 1);
        if (r < cap) part[(size_t)k * cap + r] = ((uint)d << 16) | (uint)s;
    }
}

// ---------------------------------------------------------------------------
// CSR build phase 2 (+fused GEMM1 tail blocks).
// Blocks [0,nbuck): per-bucket counting sort -> rowptr, dis, csr.
// Blocks [nbuck,...): gemm1 (x fp32 -> bufA bf16, unscaled).
// ---------------------------------------------------------------------------
__global__ __launch_bounds__(256) void k_sort_gemm1(const uint* __restrict__ part,
                                                    const int* __restrict__ gcur,
                                                    int nbuck, int cap, int n,
                                                    int* __restrict__ rowptr,
                                                    float* __restrict__ dis,
                                                    int* __restrict__ csr,
                                                    const float* __restrict__ x,
                                                    const ushort* __restrict__ wt1,
                                                    ushort* __restrict__ bufA) {
    __shared__ char smem[(64 + 128) * 136 * 2];  // 52.2 KB union
    const int tid = threadIdx.x;

    if ((int)blockIdx.x >= nbuck) {
        gemm_body<128, true>(x, wt1, bufA, n, blockIdx.x - nbuck, smem);
        return;
    }

    int* hist  = (int*)smem;          // 256 ints
    int* pfx   = hist + 256;
    int* sscan = pfx + 256;
    const int b = blockIdx.x;

    int gv = (tid < nbuck) ? min(gcur[tid], cap) : 0;
    sscan[tid] = gv;
    __syncthreads();
    for (int off = 1; off < 256; off <<= 1) {
        int t = (tid >= off) ? sscan[tid - off] : 0;
        __syncthreads();
        sscan[tid] += t;
        __syncthreads();
    }
    const int outbase = (b == 0) ? 0 : sscan[b - 1];
    const int sz = min(gcur[b], cap);
    const uint* seg = part + (size_t)b * cap;

    hist[tid] = 0;
    __syncthreads();
    for (int i = tid; i < sz; i += 256) atomicAdd(&hist[(seg[i] >> 16) & 255], 1);
    __syncthreads();

    int cnt_t = hist[tid];
    pfx[tid] = cnt_t;
    __syncthreads();
    for (int off = 1; off < 256; off <<= 1) {
        int t = (tid >= off) ? pfx[tid - off] : 0;
        __syncthreads();
        pfx[tid] += t;
        __syncthreads();
    }
    int excl = pfx[tid] - cnt_t;

    int node = b * 256 + tid;
    if (node < n) {
        rowptr[node] = outbase + excl;
        dis[node] = rsqrtf((float)(cnt_t + 1));  // +1 self loop
        if (node == n - 1) rowptr[n] = outbase + excl + cnt_t;
    }
    __syncthreads();
    pfx[tid] = excl;
    hist[tid] = 0;
    __syncthreads();
    for (int i = tid; i < sz; i += 256) {
        uint p = seg[i];
        int j = (p >> 16) & 255;
        int r = atomicAdd(&hist[j], 1);
        csr[outbase + pfx[j] + r] = (int)(p & 0xffffu);
    }
}

// ---------------------------------------------------------------------------
// Fused agg + GEMM: one block = 64 nodes, 512 threads = 8 waves.
// Stage A: every edge tile = ceil(c/16) 16-batches; no 4-batch / serial tail.
//   WITHDIS (agg1): per-edge weight dis[sidx]; padding lanes have sw=0 so
//     pad contributions self-mask (gathers hit row 0 -> L1-hot -> free).
//   !WITHDIS (agg2): input rows pre-scaled; pad masked by one cndmask.
// Stage B: MFMA 64x[COLS], B-frags from global Wt; epilogue writes
//   Y[r] = dis[r] * acc  (pre-scaled for the NEXT aggregation).
// ---------------------------------------------------------------------------
template <int COLS, bool WITHDIS>
__global__ __launch_bounds__(512) void agg_gemm(const ushort* __restrict__ H,
                                                const float* __restrict__ dis,
                                                const int* __restrict__ rowptr,
                                                const int* __restrict__ csr,
                                                const float* __restrict__ bias,
                                                const ushort* __restrict__ Wt,
                                                ushort* __restrict__ Y, int n) {
    __shared__ ushort sX[64 * 136];  // 17408 B
    const int tid = threadIdx.x;
    const int wv = tid >> 6;    // 0..7
    const int lane = tid & 63;
    const int row0 = blockIdx.x * 64;
    const uint* Hu = (const uint*)H;  // row = 64 uints (128 bf16)
    const float2 bv = ((const float2*)bias)[lane];
    const int vb = row0 + wv * 8;

#pragma unroll 1
    for (int i = 0; i < 8; ++i) {
        const int v = min(vb + i, n - 1);  // clamp: dup rows discarded at write
        // independent loads issue first; consumed at end
        uint h0 = Hu[(size_t)v * 64 + lane];
        const float dv = dis[v];
        const int e0 = rowptr[v];
        const int e1 = rowptr[v + 1];

        float ax = 0.f, ay = 0.f;
        int e = e0;
        while (e < e1) {
            const int c = min(e1 - e, 64);
            int sidx = 0; float sw = 0.0f;
            if (lane < c) { sidx = csr[e + lane]; if (WITHDIS) sw = dis[sidx]; }
#pragma unroll 1
            for (int j = 0; j < c; j += 16) {  // round-up: tail is a full predicated batch
                uint hv[16]; float wgt[16];
#pragma unroll
                for (int u = 0; u < 16; ++u) {
                    int s = __builtin_amdgcn_readlane(sidx, j + u);  // pad lanes: s=0, L1-hot
                    if (WITHDIS) wgt[u] = lane_bcast_f(sw, j + u);   // pad lanes: w=0
                    hv[u] = Hu[(size_t)s * 64 + lane];
                }
#pragma unroll
                for (int u = 0; u < 16; ++u) {
                    if (WITHDIS) {
                        ax += wgt[u] * bf_lo(hv[u]); ay += wgt[u] * bf_hi(hv[u]);
                    } else {
                        uint hm = (j + u < c) ? hv[u] : 0u;
                        ax += bf_lo(hm); ay += bf_hi(hm);
                    }
                }
            }
            e += c;
        }

        // self term
        if (WITHDIS) { ax += dv * bf_lo(h0); ay += dv * bf_hi(h0); }
        else         { ax += bf_lo(h0);      ay += bf_hi(h0); }
        float rx = fmaxf(dv * ax + bv.x, 0.f);
        float ry = fmaxf(dv * ay + bv.y, 0.f);
        ((uint*)sX)[(wv * 8 + i) * 68 + lane] = (uint)f2bf(rx) | ((uint)f2bf(ry) << 16);
    }
    __syncthreads();

    // ---- stage B ----
    constexpr int NT = COLS / 64;      // 2 (COLS=128) or 1 (COLS=64)
    constexpr int WN = COLS / 4;       // cols per wave
    const int wr = wv >> 2;            // 0..1
    const int wc = wv & 3;             // 0..3
    const int lm = lane & 15;
    const int kq = lane >> 4;

    f32x4 acc[2][NT];
#pragma unroll
    for (int mt = 0; mt < 2; ++mt)
#pragma unroll
        for (int ntn = 0; ntn < NT; ++ntn) acc[mt][ntn] = (f32x4){0.f, 0.f, 0.f, 0.f};

#pragma unroll
    for (int ks = 0; ks < 4; ++ks) {
        const int k0 = ks * 32 + kq * 8;
        short8 bfr[NT];
#pragma unroll
        for (int ntn = 0; ntn < NT; ++ntn)
            bfr[ntn] = *(const short8*)&Wt[(size_t)(wc * WN + ntn * 16 + lm) * 128 + k0];
#pragma unroll
        for (int mt = 0; mt < 2; ++mt) {
            short8 afr = *(const short8*)&sX[((wr * 2 + mt) * 16 + lm) * 136 + k0];
#pragma unroll
            for (int ntn = 0; ntn < NT; ++ntn)
                acc[mt][ntn] = __builtin_amdgcn_mfma_f32_16x16x32_bf16(afr, bfr[ntn], acc[mt][ntn], 0, 0, 0);
        }
    }

    // epilogue: pre-scale each output row by dis[r] -> next agg is weight-free
#pragma unroll
    for (int mt = 0; mt < 2; ++mt) {
        int r_base = row0 + (wr * 2 + mt) * 16 + kq * 4;
#pragma unroll
        for (int rr = 0; rr < 4; ++rr) {
            int r = r_base + rr;
            if (r < n) {
                float dr = dis[r];
#pragma unroll
                for (int ntn = 0; ntn < NT; ++ntn) {
                    int col = wc * WN + ntn * 16 + lm;
                    Y[(size_t)r * COLS + col] = f2bf(acc[mt][ntn][rr] * dr);
                }
            }
        }
    }
}

// ---------------------------------------------------------------------------
// agg64 + row-normalize (final GCN layer), target_mlp fused as tail blocks.
// Input bufC pre-scaled -> weight-free gather with predicated 16-batches.
// ---------------------------------------------------------------------------
__global__ __launch_bounds__(256) void agg64_final(const ushort* __restrict__ H,
                                                   const float* __restrict__ dis,
                                                   const int* __restrict__ rowptr,
                                                   const int* __restrict__ csr,
                                                   const float* __restrict__ bias,
                                                   float* __restrict__ out, int n, int agrid,
                                                   const float* __restrict__ y,
                                                   const float* __restrict__ gamma,
                                                   const float* __restrict__ beta,
                                                   const float* __restrict__ Wm1,
                                                   const float* __restrict__ bm1,
                                                   const float* __restrict__ Wm2,
                                                   const float* __restrict__ bm2,
                                                   float* __restrict__ out_y) {
    __shared__ float red[256];
    __shared__ float t1[128];
    __shared__ float s_mu, s_var;
    const int tid = threadIdx.x;

    if ((int)blockIdx.x >= agrid) {
        float yv = y[tid];
        red[tid] = yv;
        __syncthreads();
        for (int s = 128; s > 0; s >>= 1) {
            if (tid < s) red[tid] += red[tid + s];
            __syncthreads();
        }
        if (tid == 0) s_mu = red[0] * (1.0f / 256.0f);
        __syncthreads();
        float mu = s_mu;
        float d = yv - mu;
        red[tid] = d * d;
        __syncthreads();
        for (int s = 128; s > 0; s >>= 1) {
            if (tid < s) red[tid] += red[tid + s];
            __syncthreads();
        }
        if (tid == 0) s_var = red[0] * (1.0f / 256.0f);
        __syncthreads();

        const int row = blockIdx.x - agrid;
        float yb = (y[row] - mu) * rsqrtf(s_var + 1e-5f) * gamma[0] + beta[0];
        if (tid < 128) t1[tid] = fmaxf(yb * Wm1[tid] + bm1[tid], 0.0f);
        __syncthreads();
        if (tid < 64) {
            float acc = bm2[tid];
#pragma unroll 8
            for (int c = 0; c < 128; ++c) acc += t1[c] * Wm2[c * 64 + tid];
            float ss = acc * acc;
#pragma unroll
            for (int m = 1; m < 64; m <<= 1) ss += __shfl_xor(ss, m, 64);
            out_y[row * 64 + tid] = acc / fmaxf(sqrtf(ss), 1e-12f);
        }
        return;
    }

    const int wid = blockIdx.x * 4 + (tid >> 6);
    const int lane = tid & 63;
    if (wid >= n) return;
    const int v = wid;
    // independent loads issue together; self term consumed at end
    ushort h0 = H[(size_t)v * 64 + lane];
    const float dv = dis[v];
    const int e0 = rowptr[v];
    const int e1 = rowptr[v + 1];

    float acc = 0.0f;
    int e = e0;
    while (e < e1) {
        const int c = min(e1 - e, 64);
        int sidx = 0;
        if (lane < c) sidx = csr[e + lane];
#pragma unroll 1
        for (int j = 0; j < c; j += 16) {
            ushort hv[16];
#pragma unroll
            for (int u = 0; u < 16; ++u) {
                int s = __builtin_amdgcn_readlane(sidx, j + u);
                hv[u] = H[(size_t)s * 64 + lane];
            }
#pragma unroll
            for (int u = 0; u < 16; ++u) {
                uint hm = (j + u < c) ? (uint)hv[u] : 0u;
                acc += bf_lo(hm);
            }
        }
        e += c;
    }

    acc += bf_lo((uint)h0);  // pre-scaled self term
    float r = dv * acc + bias[lane];
    float ss = r * r;
#pragma unroll
    for (int m = 1; m < 64; m <<= 1) ss += __shfl_xor(ss, m, 64);
    r = r / fmaxf(sqrtf(ss), 1e-12f);
    out[(size_t)v * 64 + lane] = r;
}

// ---------------------------------------------------------------------------
extern "C" void kernel_launch(void* const* d_in, const int* in_sizes, int n_in,
                              void* d_out, int out_size, void* d_ws, size_t ws_size,
                              hipStream_t stream) {
    const float* x     = (const float*)d_in[0];
    const float* y     = (const float*)d_in[1];
    const int*   edge  = (const int*)d_in[2];
    const float* W1    = (const float*)d_in[3];
    const float* b1    = (const float*)d_in[4];
    const float* W2    = (const float*)d_in[5];
    const float* b2    = (const float*)d_in[6];
    const float* W3    = (const float*)d_in[7];
    const float* b3    = (const float*)d_in[8];
    const float* bng   = (const float*)d_in[9];
    const float* bnb   = (const float*)d_in[10];
    const float* Wm1   = (const float*)d_in[11];
    const float* bm1   = (const float*)d_in[12];
    const float* Wm2   = (const float*)d_in[13];
    const float* bm2   = (const float*)d_in[14];

    const int n = in_sizes[0] / 128;  // 50000
    const int E = in_sizes[2] / 2;    // 800000
    const int* src = edge;
    const int* dst = edge + E;

    const int nbuck = (n + 255) / 256;                 // 196
    const int cap = E / nbuck + E / nbuck / 4 + 1024;  // mean + 25% + slack

    size_t off = 0;
    auto carve = [&](size_t bytes) {
        size_t p = off;
        off = (off + bytes + 255) & ~(size_t)255;
        return p;
    };
    char* ws = (char*)d_ws;
    int*    gcur    = (int*)(ws + carve(256 * 4));
    uint*   part    = (uint*)(ws + carve((size_t)nbuck * cap * 4));
    int*    rowptr  = (int*)(ws + carve((size_t)(n + 1) * 4));
    int*    csr     = (int*)(ws + carve((size_t)E * 4));
    float*  dis     = (float*)(ws + carve((size_t)n * 4));
    ushort* wt1     = (ushort*)(ws + carve(128 * 128 * 2));
    ushort* wt2     = (ushort*)(ws + carve(128 * 128 * 2));
    ushort* wt3     = (ushort*)(ws + carve(64 * 128 * 2));
    ushort* bufA    = (ushort*)(ws + carve((size_t)n * 128 * 2));
    ushort* bufB    = (ushort*)(ws + carve((size_t)n * 128 * 2));
    ushort* bufC    = (ushort*)(ws + carve((size_t)n * 64 * 2));
    (void)ws_size; (void)n_in; (void)out_size;

    float* x_emb = (float*)d_out;
    float* y_emb = (float*)d_out + (size_t)n * 64;

    const int pblocks = (E + PCHUNK - 1) / PCHUNK;  // 782
    const int ggrid = (n + 63) / 64;                // 782
    const int agrid = (n + 3) / 4;                  // 12500

    hipMemsetAsync(gcur, 0, 256 * 4, stream);
    k_partition<<<pblocks + 160, 256, 0, stream>>>(src, dst, E, nbuck, cap, pblocks,
                                                   gcur, part, W1, W2, W3, wt1, wt2, wt3);
    // bucket sort (196 blocks) + gemm1 (782 blocks) run concurrently
    k_sort_gemm1<<<nbuck + ggrid, 256, 0, stream>>>(part, gcur, nbuck, cap, n,
                                                    rowptr, dis, csr, x, wt1, bufA);

    // fused: agg(layer1, per-edge dis) -> GEMM W2, write bufB pre-scaled
    agg_gemm<128, true><<<ggrid, 512, 0, stream>>>(bufA, dis, rowptr, csr, b1, wt2, bufB, n);
    // fused: agg(layer2, weight-free) -> GEMM W3, write bufC pre-scaled
    agg_gemm<64, false><<<ggrid, 512, 0, stream>>>(bufB, dis, rowptr, csr, b2, wt3, bufC, n);
    // final agg (weight-free) + normalize (+ target MLP tail blocks)
    agg64_final<<<agrid + 256, 256, 0, stream>>>(bufC, dis, rowptr, csr, b3, x_emb, n, agrid,
                                                 y, bng, bnb, Wm1, bm1, Wm2, bm2, y_emb);
}

// Round 6
// 246.807 us; speedup vs baseline: 1.1968x; 1.0253x over previous
//
#include <hip/hip_runtime.h>
#include <hip/hip_bf16.h>

typedef __attribute__((ext_vector_type(8))) short short8;
typedef __attribute__((ext_vector_type(4))) float f32x4;

__device__ __forceinline__ ushort f2bf(float f) {
    union { float f; uint u; } v; v.f = f;
    uint u = v.u;
    return (ushort)((u + 0x7fffu + ((u >> 16) & 1u)) >> 16);  // RNE
}
__device__ __forceinline__ float bf_lo(uint u) { return __uint_as_float(u << 16); }
__device__ __forceinline__ float bf_hi(uint u) { return __uint_as_float(u & 0xffff0000u); }

// ---------------------------------------------------------------------------
// bf16 MFMA GEMM body: Y[n,COLS](bf16) = X[n,128] @ Wt[COLS][128](bf16)
// DISSCALE: multiply output row r by dis[r] (pre-scale for next aggregation).
// smem >= (64+COLS)*136*2 B. 256-thread blocks.
// ---------------------------------------------------------------------------
template <int COLS, bool F32IN, bool DISSCALE>
__device__ __forceinline__ void gemm_body(const void* __restrict__ Xin,
                                          const ushort* __restrict__ Wt,
                                          ushort* __restrict__ Y, int n,
                                          int bid, char* smem,
                                          const float* __restrict__ dis) {
    constexpr int LDW = 136;  // +8 pad
    ushort* sX = (ushort*)smem;
    ushort* sW = sX + 64 * LDW;
    const int tid = threadIdx.x;
    const int row0 = bid * 64;

    if (F32IN) {
        const float* Xf = (const float*)Xin;
#pragma unroll
        for (int i = 0; i < 8; ++i) {
            int idx = i * 256 + tid;
            int r = idx >> 5, kc = idx & 31;
            int gr = min(row0 + r, n - 1);
            float4 v = *(const float4*)&Xf[(size_t)gr * 128 + kc * 4];
            ushort4 o;
            o.x = f2bf(v.x); o.y = f2bf(v.y); o.z = f2bf(v.z); o.w = f2bf(v.w);
            *(ushort4*)&sX[r * LDW + kc * 4] = o;
        }
    } else {
        const ushort* Xb = (const ushort*)Xin;
#pragma unroll
        for (int i = 0; i < 4; ++i) {
            int idx = i * 256 + tid;
            int r = idx >> 4, kc = idx & 15;
            int gr = min(row0 + r, n - 1);
            uint4 v = *(const uint4*)&Xb[(size_t)gr * 128 + kc * 8];
            *(uint4*)&sX[r * LDW + kc * 8] = v;
        }
    }
#pragma unroll
    for (int c = tid; c < COLS * 16; c += 256) {
        int r = c >> 4, kc = c & 15;
        uint4 v = *(const uint4*)&Wt[(size_t)r * 128 + kc * 8];
        *(uint4*)&sW[r * LDW + kc * 8] = v;
    }
    __syncthreads();

    constexpr int NT = (COLS == 128) ? 2 : 1;
    constexpr int WN = COLS / 4;
    const int w = tid >> 6;
    const int lane = tid & 63;
    const int lm = lane & 15;
    const int kq = lane >> 4;

    f32x4 acc[4][NT];
#pragma unroll
    for (int mt = 0; mt < 4; ++mt)
#pragma unroll
        for (int ntn = 0; ntn < NT; ++ntn) acc[mt][ntn] = (f32x4){0.f, 0.f, 0.f, 0.f};

#pragma unroll
    for (int ks = 0; ks < 4; ++ks) {
        const int k0 = ks * 32 + kq * 8;
        short8 bfr[NT];
#pragma unroll
        for (int ntn = 0; ntn < NT; ++ntn)
            bfr[ntn] = *(const short8*)&sW[(w * WN + ntn * 16 + lm) * LDW + k0];
#pragma unroll
        for (int mt = 0; mt < 4; ++mt) {
            short8 afr = *(const short8*)&sX[(mt * 16 + lm) * LDW + k0];
#pragma unroll
            for (int ntn = 0; ntn < NT; ++ntn)
                acc[mt][ntn] = __builtin_amdgcn_mfma_f32_16x16x32_bf16(afr, bfr[ntn], acc[mt][ntn], 0, 0, 0);
        }
    }

#pragma unroll
    for (int mt = 0; mt < 4; ++mt) {
        int r_base = row0 + mt * 16 + kq * 4;
#pragma unroll
        for (int rr = 0; rr < 4; ++rr) {
            int r = r_base + rr;
            if (r < n) {
                float dr = DISSCALE ? dis[r] : 1.0f;
#pragma unroll
                for (int ntn = 0; ntn < NT; ++ntn) {
                    int col = w * WN + ntn * 16 + lm;
                    Y[(size_t)r * COLS + col] = f2bf(acc[mt][ntn][rr] * dr);
                }
            }
        }
    }
}

template <int COLS, bool F32IN, bool DISSCALE>
__global__ __launch_bounds__(256) void gemm_mfma(const void* __restrict__ Xin,
                                                 const ushort* __restrict__ Wt,
                                                 ushort* __restrict__ Y, int n,
                                                 const float* __restrict__ dis) {
    __shared__ char smem[(64 + COLS) * 136 * 2];
    gemm_body<COLS, F32IN, DISSCALE>(Xin, Wt, Y, n, blockIdx.x, smem, dis);
}

// ---------------------------------------------------------------------------
// CSR build phase 1: coarse partition by dst>>8 (+fused weight cast tail).
// Edges packed (dst<<16)|src. No global atomics. PCHUNK=1024 -> 782 blocks.
// ---------------------------------------------------------------------------
#define PCHUNK 1024

__global__ __launch_bounds__(256) void k_partition(const int* __restrict__ src,
                                                   const int* __restrict__ dst, int E,
                                                   int nbuck, int cap, int pblocks,
                                                   int* __restrict__ gcur,
                                                   uint* __restrict__ part,
                                                   const float* __restrict__ W1,
                                                   const float* __restrict__ W2,
                                                   const float* __restrict__ W3,
                                                   ushort* __restrict__ wt1,
                                                   ushort* __restrict__ wt2,
                                                   ushort* __restrict__ wt3) {
    __shared__ int hist[256];
    __shared__ int base[256];
    __shared__ int cnt2[256];
    const int tid = threadIdx.x;

    if ((int)blockIdx.x >= pblocks) {
        int i = (blockIdx.x - pblocks) * 256 + tid;
        if (i < 16384) {
            int k = i >> 7, nn = i & 127;
            wt1[nn * 128 + k] = f2bf(W1[i]);
        } else if (i < 32768) {
            int j = i - 16384;
            int k = j >> 7, nn = j & 127;
            wt2[nn * 128 + k] = f2bf(W2[j]);
        } else if (i < 40960) {
            int j = i - 32768;
            int k = j >> 6, nn = j & 63;
            wt3[nn * 128 + k] = f2bf(W3[j]);
        }
        return;
    }

    const int s0 = blockIdx.x * PCHUNK;
    const int send = min(s0 + PCHUNK, E);
    hist[tid] = 0;
    cnt2[tid] = 0;
    __syncthreads();
    for (int i = s0 + tid; i < send; i += 256) {
        int d = dst[i];
        atomicAdd(&hist[d >> 8], 1);
    }
    __syncthreads();
    if (tid < nbuck && hist[tid] > 0) base[tid] = atomicAdd(&gcur[tid], hist[tid]);
    __syncthreads();
    for (int i = s0 + tid; i < send; i += 256) {
        int d = dst[i];
        int s = src[i];
        int k = d >> 8;
        int r = base[k] + atomicAdd(&cnt2[k], 1);
        if (r < cap) part[(size_t)k * cap + r] = ((uint)d << 16) | (uint)s;
    }
}

// ---------------------------------------------------------------------------
// CSR build phase 2 (+fused GEMM1 tail blocks).
// ---------------------------------------------------------------------------
__global__ __launch_bounds__(256) void k_sort_gemm1(const uint* __restrict__ part,
                                                    const int* __restrict__ gcur,
                                                    int nbuck, int cap, int n,
                                                    int* __restrict__ rowptr,
                                                    float* __restrict__ dis,
                                                    int* __restrict__ csr,
                                                    const float* __restrict__ x,
                                                    const ushort* __restrict__ wt1,
                                                    ushort* __restrict__ bufA) {
    __shared__ char smem[(64 + 128) * 136 * 2];  // 52.2 KB union
    const int tid = threadIdx.x;

    if ((int)blockIdx.x >= nbuck) {
        gemm_body<128, true, false>(x, wt1, bufA, n, blockIdx.x - nbuck, smem, nullptr);
        return;
    }

    int* hist  = (int*)smem;          // 256 ints
    int* pfx   = hist + 256;
    int* sscan = pfx + 256;
    const int b = blockIdx.x;

    int gv = (tid < nbuck) ? min(gcur[tid], cap) : 0;
    sscan[tid] = gv;
    __syncthreads();
    for (int off = 1; off < 256; off <<= 1) {
        int t = (tid >= off) ? sscan[tid - off] : 0;
        __syncthreads();
        sscan[tid] += t;
        __syncthreads();
    }
    const int outbase = (b == 0) ? 0 : sscan[b - 1];
    const int sz = min(gcur[b], cap);
    const uint* seg = part + (size_t)b * cap;

    hist[tid] = 0;
    __syncthreads();
    for (int i = tid; i < sz; i += 256) atomicAdd(&hist[(seg[i] >> 16) & 255], 1);
    __syncthreads();

    int cnt_t = hist[tid];
    pfx[tid] = cnt_t;
    __syncthreads();
    for (int off = 1; off < 256; off <<= 1) {
        int t = (tid >= off) ? pfx[tid - off] : 0;
        __syncthreads();
        pfx[tid] += t;
        __syncthreads();
    }
    int excl = pfx[tid] - cnt_t;

    int node = b * 256 + tid;
    if (node < n) {
        rowptr[node] = outbase + excl;
        dis[node] = rsqrtf((float)(cnt_t + 1));  // +1 self loop
        if (node == n - 1) rowptr[n] = outbase + excl + cnt_t;
    }
    __syncthreads();
    pfx[tid] = excl;
    hist[tid] = 0;
    __syncthreads();
    for (int i = tid; i < sz; i += 256) {
        uint p = seg[i];
        int j = (p >> 16) & 255;
        int r = atomicAdd(&hist[j], 1);
        csr[outbase + pfx[j] + r] = (int)(p & 0xffffu);
    }
}

// ---------------------------------------------------------------------------
// agg128: one WAVE per node (max TLP: 12500 blocks, 50k waves).
// Gather 4 rows per dwordx4 instruction: lane = (group g=lane>>4, slice
// q=lane&15); lane loads 16B (cols 8q..8q+7) of row s_g. Row indices fan out
// via ds_bpermute of the csr tile. Padding rows self-mask via weight 0.
// Cross-group merge: 2-step shfl_xor butterfly. WITHDIS: per-edge dis weight
// (layer 1); else weight-free (input pre-scaled by GEMM epilogue).
// out[v] = relu(dv*(sum w_s H[s] + selfw*H[v]) + b), bf16.
// ---------------------------------------------------------------------------
template <bool WITHDIS>
__global__ __launch_bounds__(256) void agg128(const ushort* __restrict__ H,
                                              const float* __restrict__ dis,
                                              const int* __restrict__ rowptr,
                                              const int* __restrict__ csr,
                                              const float* __restrict__ bias,
                                              ushort* __restrict__ Y, int n) {
    const int wid = blockIdx.x * 4 + (threadIdx.x >> 6);
    if (wid >= n) return;
    const int lane = threadIdx.x & 63;
    const int g = lane >> 4;   // row group 0..3
    const int q = lane & 15;   // col slice: cols 8q..8q+7
    const int v = wid;

    const uint4* Hq = (const uint4*)H;  // row = 16 x uint4 (256B)
    // independent loads issue first
    uint4 selfv = Hq[(size_t)v * 16 + q];
    const float dv = dis[v];
    const int e0 = rowptr[v];
    const int e1 = rowptr[v + 1];

    float acc[8];
#pragma unroll
    for (int t = 0; t < 8; ++t) acc[t] = 0.f;

    int e = e0;
    while (e < e1) {
        const int c = min(e1 - e, 64);
        int sidx = 0; float sw = 0.0f;
        if (lane < c) { sidx = csr[e + lane]; if (WITHDIS) sw = dis[sidx]; }
#pragma unroll 1
        for (int j = 0; j < c; j += 16) {  // 16 rows per chunk = 4 dwordx4 loads
            uint4 hv[4]; float wrow[4];
#pragma unroll
            for (int k = 0; k < 4; ++k) {
                int srcLane = j + k * 4 + g;  // always < 64
                int srow = __builtin_amdgcn_ds_bpermute(srcLane << 2, sidx);
                if (WITHDIS)
                    wrow[k] = __uint_as_float(__builtin_amdgcn_ds_bpermute(
                        srcLane << 2, __float_as_uint(sw)));  // pad lanes: 0
                else
                    wrow[k] = (srcLane < c) ? 1.0f : 0.0f;
                hv[k] = Hq[(size_t)srow * 16 + q];
            }
#pragma unroll
            for (int k = 0; k < 4; ++k) {
                acc[0] += wrow[k] * bf_lo(hv[k].x); acc[1] += wrow[k] * bf_hi(hv[k].x);
                acc[2] += wrow[k] * bf_lo(hv[k].y); acc[3] += wrow[k] * bf_hi(hv[k].y);
                acc[4] += wrow[k] * bf_lo(hv[k].z); acc[5] += wrow[k] * bf_hi(hv[k].z);
                acc[6] += wrow[k] * bf_lo(hv[k].w); acc[7] += wrow[k] * bf_hi(hv[k].w);
            }
        }
        e += c;
    }

    // merge the 4 row-groups (each lane ends with full neighbor sum for its cols)
#pragma unroll
    for (int t = 0; t < 8; ++t) {
        acc[t] += __shfl_xor(acc[t], 16);
        acc[t] += __shfl_xor(acc[t], 32);
    }
    // self term
    const float selfw = WITHDIS ? dv : 1.0f;
    acc[0] += selfw * bf_lo(selfv.x); acc[1] += selfw * bf_hi(selfv.x);
    acc[2] += selfw * bf_lo(selfv.y); acc[3] += selfw * bf_hi(selfv.y);
    acc[4] += selfw * bf_lo(selfv.z); acc[5] += selfw * bf_hi(selfv.z);
    acc[6] += selfw * bf_lo(selfv.w); acc[7] += selfw * bf_hi(selfv.w);

    if (g == 0) {  // groups hold duplicates post-butterfly; one writes
        float4 b0 = *(const float4*)&bias[q * 8];
        float4 b1 = *(const float4*)&bias[q * 8 + 4];
        float r0 = fmaxf(dv * acc[0] + b0.x, 0.f), r1 = fmaxf(dv * acc[1] + b0.y, 0.f);
        float r2 = fmaxf(dv * acc[2] + b0.z, 0.f), r3 = fmaxf(dv * acc[3] + b0.w, 0.f);
        float r4 = fmaxf(dv * acc[4] + b1.x, 0.f), r5 = fmaxf(dv * acc[5] + b1.y, 0.f);
        float r6 = fmaxf(dv * acc[6] + b1.z, 0.f), r7 = fmaxf(dv * acc[7] + b1.w, 0.f);
        uint4 o;
        o.x = (uint)f2bf(r0) | ((uint)f2bf(r1) << 16);
        o.y = (uint)f2bf(r2) | ((uint)f2bf(r3) << 16);
        o.z = (uint)f2bf(r4) | ((uint)f2bf(r5) << 16);
        o.w = (uint)f2bf(r6) | ((uint)f2bf(r7) << 16);
        *(uint4*)&Y[(size_t)v * 128 + q * 8] = o;
    }
}

// ---------------------------------------------------------------------------
// agg64 + row-normalize (final GCN layer), target_mlp fused as tail blocks.
// 8 rows per dwordx4 instruction (row = 128B): g=lane>>3, q=lane&7.
// Input bufC pre-scaled -> weight-free.
// ---------------------------------------------------------------------------
__global__ __launch_bounds__(256) void agg64_final(const ushort* __restrict__ H,
                                                   const float* __restrict__ dis,
                                                   const int* __restrict__ rowptr,
                                                   const int* __restrict__ csr,
                                                   const float* __restrict__ bias,
                                                   float* __restrict__ out, int n, int agrid,
                                                   const float* __restrict__ y,
                                                   const float* __restrict__ gamma,
                                                   const float* __restrict__ beta,
                                                   const float* __restrict__ Wm1,
                                                   const float* __restrict__ bm1,
                                                   const float* __restrict__ Wm2,
                                                   const float* __restrict__ bm2,
                                                   float* __restrict__ out_y) {
    __shared__ float red[256];
    __shared__ float t1[128];
    __shared__ float s_mu, s_var;
    const int tid = threadIdx.x;

    if ((int)blockIdx.x >= agrid) {
        float yv = y[tid];
        red[tid] = yv;
        __syncthreads();
        for (int s = 128; s > 0; s >>= 1) {
            if (tid < s) red[tid] += red[tid + s];
            __syncthreads();
        }
        if (tid == 0) s_mu = red[0] * (1.0f / 256.0f);
        __syncthreads();
        float mu = s_mu;
        float d = yv - mu;
        red[tid] = d * d;
        __syncthreads();
        for (int s = 128; s > 0; s >>= 1) {
            if (tid < s) red[tid] += red[tid + s];
            __syncthreads();
        }
        if (tid == 0) s_var = red[0] * (1.0f / 256.0f);
        __syncthreads();

        const int row = blockIdx.x - agrid;
        float yb = (y[row] - mu) * rsqrtf(s_var + 1e-5f) * gamma[0] + beta[0];
        if (tid < 128) t1[tid] = fmaxf(yb * Wm1[tid] + bm1[tid], 0.0f);
        __syncthreads();
        if (tid < 64) {
            float acc = bm2[tid];
#pragma unroll 8
            for (int c = 0; c < 128; ++c) acc += t1[c] * Wm2[c * 64 + tid];
            float ss = acc * acc;
#pragma unroll
            for (int m = 1; m < 64; m <<= 1) ss += __shfl_xor(ss, m, 64);
            out_y[row * 64 + tid] = acc / fmaxf(sqrtf(ss), 1e-12f);
        }
        return;
    }

    const int wid = blockIdx.x * 4 + (tid >> 6);
    if (wid >= n) return;
    const int lane = tid & 63;
    const int g = lane >> 3;  // row group 0..7
    const int q = lane & 7;   // col slice: cols 8q..8q+7
    const int v = wid;

    const uint4* Hq = (const uint4*)H;  // row = 8 x uint4 (128B)
    uint4 selfv = Hq[(size_t)v * 8 + q];
    const float dv = dis[v];
    const int e0 = rowptr[v];
    const int e1 = rowptr[v + 1];

    float acc[8];
#pragma unroll
    for (int t = 0; t < 8; ++t) acc[t] = 0.f;

    int e = e0;
    while (e < e1) {
        const int c = min(e1 - e, 64);
        int sidx = 0;
        if (lane < c) sidx = csr[e + lane];
#pragma unroll 1
        for (int j = 0; j < c; j += 16) {  // 16 rows per chunk = 2 dwordx4 loads
            uint4 hv[2]; float wrow[2];
#pragma unroll
            for (int k = 0; k < 2; ++k) {
                int srcLane = j + k * 8 + g;
                int srow = __builtin_amdgcn_ds_bpermute(srcLane << 2, sidx);
                wrow[k] = (srcLane < c) ? 1.0f : 0.0f;
                hv[k] = Hq[(size_t)srow * 8 + q];
            }
#pragma unroll
            for (int k = 0; k < 2; ++k) {
                acc[0] += wrow[k] * bf_lo(hv[k].x); acc[1] += wrow[k] * bf_hi(hv[k].x);
                acc[2] += wrow[k] * bf_lo(hv[k].y); acc[3] += wrow[k] * bf_hi(hv[k].y);
                acc[4] += wrow[k] * bf_lo(hv[k].z); acc[5] += wrow[k] * bf_hi(hv[k].z);
                acc[6] += wrow[k] * bf_lo(hv[k].w); acc[7] += wrow[k] * bf_hi(hv[k].w);
            }
        }
        e += c;
    }

#pragma unroll
    for (int t = 0; t < 8; ++t) {
        acc[t] += __shfl_xor(acc[t], 8);
        acc[t] += __shfl_xor(acc[t], 16);
        acc[t] += __shfl_xor(acc[t], 32);
    }
    acc[0] += bf_lo(selfv.x); acc[1] += bf_hi(selfv.x);
    acc[2] += bf_lo(selfv.y); acc[3] += bf_hi(selfv.y);
    acc[4] += bf_lo(selfv.z); acc[5] += bf_hi(selfv.z);
    acc[6] += bf_lo(selfv.w); acc[7] += bf_hi(selfv.w);

    float4 b0 = *(const float4*)&bias[q * 8];
    float4 b1 = *(const float4*)&bias[q * 8 + 4];
    float r[8];
    r[0] = dv * acc[0] + b0.x; r[1] = dv * acc[1] + b0.y;
    r[2] = dv * acc[2] + b0.z; r[3] = dv * acc[3] + b0.w;
    r[4] = dv * acc[4] + b1.x; r[5] = dv * acc[5] + b1.y;
    r[6] = dv * acc[6] + b1.z; r[7] = dv * acc[7] + b1.w;
    float ss = 0.f;
#pragma unroll
    for (int t = 0; t < 8; ++t) ss += r[t] * r[t];
    ss += __shfl_xor(ss, 1);
    ss += __shfl_xor(ss, 2);
    ss += __shfl_xor(ss, 4);
    float inv = 1.0f / fmaxf(sqrtf(ss), 1e-12f);
    if (g == 0) {  // 8 lanes write 32B each = 256B row
        float4 o0 = {r[0] * inv, r[1] * inv, r[2] * inv, r[3] * inv};
        float4 o1 = {r[4] * inv, r[5] * inv, r[6] * inv, r[7] * inv};
        *(float4*)&out[(size_t)v * 64 + q * 8] = o0;
        *(float4*)&out[(size_t)v * 64 + q * 8 + 4] = o1;
    }
}

// ---------------------------------------------------------------------------
extern "C" void kernel_launch(void* const* d_in, const int* in_sizes, int n_in,
                              void* d_out, int out_size, void* d_ws, size_t ws_size,
                              hipStream_t stream) {
    const float* x     = (const float*)d_in[0];
    const float* y     = (const float*)d_in[1];
    const int*   edge  = (const int*)d_in[2];
    const float* W1    = (const float*)d_in[3];
    const float* b1    = (const float*)d_in[4];
    const float* W2    = (const float*)d_in[5];
    const float* b2    = (const float*)d_in[6];
    const float* W3    = (const float*)d_in[7];
    const float* b3    = (const float*)d_in[8];
    const float* bng   = (const float*)d_in[9];
    const float* bnb   = (const float*)d_in[10];
    const float* Wm1   = (const float*)d_in[11];
    const float* bm1   = (const float*)d_in[12];
    const float* Wm2   = (const float*)d_in[13];
    const float* bm2   = (const float*)d_in[14];

    const int n = in_sizes[0] / 128;  // 50000
    const int E = in_sizes[2] / 2;    // 800000
    const int* src = edge;
    const int* dst = edge + E;

    const int nbuck = (n + 255) / 256;                 // 196
    const int cap = E / nbuck + E / nbuck / 4 + 1024;  // mean + 25% + slack

    size_t off = 0;
    auto carve = [&](size_t bytes) {
        size_t p = off;
        off = (off + bytes + 255) & ~(size_t)255;
        return p;
    };
    char* ws = (char*)d_ws;
    int*    gcur    = (int*)(ws + carve(256 * 4));
    uint*   part    = (uint*)(ws + carve((size_t)nbuck * cap * 4));
    int*    rowptr  = (int*)(ws + carve((size_t)(n + 1) * 4));
    int*    csr     = (int*)(ws + carve((size_t)E * 4));
    float*  dis     = (float*)(ws + carve((size_t)n * 4));
    ushort* wt1     = (ushort*)(ws + carve(128 * 128 * 2));
    ushort* wt2     = (ushort*)(ws + carve(128 * 128 * 2));
    ushort* wt3     = (ushort*)(ws + carve(64 * 128 * 2));
    ushort* bufA    = (ushort*)(ws + carve((size_t)n * 128 * 2));
    ushort* bufB    = (ushort*)(ws + carve((size_t)n * 128 * 2));
    ushort* bufC    = (ushort*)(ws + carve((size_t)n * 64 * 2));
    (void)ws_size; (void)n_in; (void)out_size;

    float* x_emb = (float*)d_out;
    float* y_emb = (float*)d_out + (size_t)n * 64;

    const int pblocks = (E + PCHUNK - 1) / PCHUNK;  // 782
    const int ggrid = (n + 63) / 64;                // 782
    const int agrid = (n + 3) / 4;                  // 12500

    hipMemsetAsync(gcur, 0, 256 * 4, stream);
    k_partition<<<pblocks + 160, 256, 0, stream>>>(src, dst, E, nbuck, cap, pblocks,
                                                   gcur, part, W1, W2, W3, wt1, wt2, wt3);
    // bucket sort (196 blocks) + gemm1 (782 blocks) run concurrently
    k_sort_gemm1<<<nbuck + ggrid, 256, 0, stream>>>(part, gcur, nbuck, cap, n,
                                                    rowptr, dis, csr, x, wt1, bufA);

    // layer 1: agg (per-edge dis) -> relu rows
    agg128<true><<<agrid, 256, 0, stream>>>(bufA, dis, rowptr, csr, b1, bufB, n);
    // gemm W2, output pre-scaled by dis[r]
    gemm_mfma<128, false, true><<<ggrid, 256, 0, stream>>>(bufB, wt2, bufA, n, dis);
    // layer 2: weight-free agg
    agg128<false><<<agrid, 256, 0, stream>>>(bufA, dis, rowptr, csr, b2, bufB, n);
    // gemm W3, output pre-scaled
    gemm_mfma<64, false, true><<<ggrid, 256, 0, stream>>>(bufB, wt3, bufC, n, dis);
    // final agg (weight-free) + normalize (+ target MLP tail blocks)
    agg64_final<<<agrid + 256, 256, 0, stream>>>(bufC, dis, rowptr, csr, b3, x_emb, n, agrid,
                                                 y, bng, bnb, Wm1, bm1, Wm2, bm2, y_emb);
}